// Round 1
// baseline (287.361 us; speedup 1.0000x reference)
//
#include <hip/hip_runtime.h>
#include <hip/hip_bf16.h>
#include <math.h>

// MoE Router V2: x(16384,2048) fp32, W(128,2048) fp32, bias(128) fp32
// out = [weights(16384,8) fp32 | indices(16384,8) as fp32]
//
// Kernel A: fp32 logits GEMM with split-K, partials in d_ws.
//   tile: 128 tokens x 128 experts per 256-thread block, 8x8 per thread.
// Kernel B: combine partials + softmax + stable top-8 + L2 normalize.

#define MT   128   // tokens per tile
#define NE   128   // experts (fixed)
#define DC   32    // d-chunk staged in LDS
#define PAD  132   // padded row length (keeps 16B align, 4-way max conflict)
#define DMODEL 2048

__global__ __launch_bounds__(256, 2) void logits_partial(
    const float* __restrict__ x, const float* __restrict__ w,
    float* __restrict__ part, int dPerSplit, int N) {
  __shared__ float xs[DC][PAD];
  __shared__ float wsm[DC][PAD];
  const int tid = threadIdx.x;
  const int tx = tid & 15;        // expert group 0..15
  const int ty = tid >> 4;        // token group 0..15
  const int e0 = tx * 8;
  const int t0 = ty * 8;
  const size_t tokBase = (size_t)blockIdx.x * MT;
  const int d0 = blockIdx.y * dPerSplit;

  float acc[8][8];
#pragma unroll
  for (int i = 0; i < 8; ++i)
#pragma unroll
    for (int j = 0; j < 8; ++j) acc[i][j] = 0.f;

  for (int dc = 0; dc < dPerSplit; dc += DC) {
    __syncthreads();
    // stage x[128 tok][32 d] and w[128 exp][32 d], transposed into LDS [d][row]
#pragma unroll
    for (int j = 0; j < 4; ++j) {
      const int r  = (tid >> 3) + j * 32;   // token / expert row
      const int cc = tid & 7;               // float4 column (d = 4*cc)
      const float4 xv = *(const float4*)(x + (tokBase + r) * DMODEL + d0 + dc + cc * 4);
      const float4 wv = *(const float4*)(w + (size_t)r * DMODEL + d0 + dc + cc * 4);
      const int dd = cc * 4;
      xs[dd + 0][r] = xv.x; xs[dd + 1][r] = xv.y;
      xs[dd + 2][r] = xv.z; xs[dd + 3][r] = xv.w;
      wsm[dd + 0][r] = wv.x; wsm[dd + 1][r] = wv.y;
      wsm[dd + 2][r] = wv.z; wsm[dd + 3][r] = wv.w;
    }
    __syncthreads();
#pragma unroll 8
    for (int d = 0; d < DC; ++d) {
      const float4 xa = *(const float4*)&xs[d][t0];
      const float4 xb = *(const float4*)&xs[d][t0 + 4];
      const float4 wa = *(const float4*)&wsm[d][e0];
      const float4 wb = *(const float4*)&wsm[d][e0 + 4];
      const float xr[8] = {xa.x, xa.y, xa.z, xa.w, xb.x, xb.y, xb.z, xb.w};
      const float wr[8] = {wa.x, wa.y, wa.z, wa.w, wb.x, wb.y, wb.z, wb.w};
#pragma unroll
      for (int i = 0; i < 8; ++i)
#pragma unroll
        for (int jj = 0; jj < 8; ++jj)
          acc[i][jj] = fmaf(xr[i], wr[jj], acc[i][jj]);
    }
  }

  const size_t pBase = ((size_t)blockIdx.y * N + tokBase + t0) * NE + e0;
#pragma unroll
  for (int i = 0; i < 8; ++i) {
    float4 v0 = make_float4(acc[i][0], acc[i][1], acc[i][2], acc[i][3]);
    float4 v1 = make_float4(acc[i][4], acc[i][5], acc[i][6], acc[i][7]);
    *(float4*)(part + pBase + (size_t)i * NE)     = v0;
    *(float4*)(part + pBase + (size_t)i * NE + 4) = v1;
  }
}

// One wave (64 lanes) per token; lane owns experts {lane, lane+64}.
__global__ __launch_bounds__(256) void router_topk(
    const float* __restrict__ part, const float* __restrict__ bias,
    float* __restrict__ outW, float* __restrict__ outI, int KS, int N) {
  const int wave = threadIdx.x >> 6;
  const int lane = threadIdx.x & 63;
  const int token = blockIdx.x * 4 + wave;
  if (token >= N) return;

  // deterministic combine of split-K partials (fixed order k=0..KS-1)
  float l0 = 0.f, l1 = 0.f;
  for (int k = 0; k < KS; ++k) {
    const float* p = part + ((size_t)k * N + token) * NE;
    l0 += p[lane];
    l1 += p[lane + 64];
  }

  // softmax over 128 experts
  float m = fmaxf(l0, l1);
#pragma unroll
  for (int off = 1; off < 64; off <<= 1) m = fmaxf(m, __shfl_xor(m, off));
  const float ev0 = __expf(l0 - m);
  const float ev1 = __expf(l1 - m);
  float zs = ev0 + ev1;
#pragma unroll
  for (int off = 1; off < 64; off <<= 1) zs += __shfl_xor(zs, off);
  const float s0 = ev0 / zs;
  const float s1 = ev1 / zs;

  // bias-adjusted selection keys (bias affects selection only)
  float b0 = s0 + bias[lane];
  float b1 = s1 + bias[lane + 64];

  float myv = 0.f;
  int myi = 0;
  float ss = 0.f;
#pragma unroll
  for (int r = 0; r < 8; ++r) {
    // lane-local best (tie -> smaller index; lane < lane+64 so >=)
    float key; int idx;
    if (b0 >= b1) { key = b0; idx = lane; }
    else          { key = b1; idx = lane + 64; }
    // wave argmax, stable (tie -> smaller index), matches lax.top_k
#pragma unroll
    for (int off = 1; off < 64; off <<= 1) {
      const float k2 = __shfl_xor(key, off);
      const int   i2 = __shfl_xor(idx, off);
      if (k2 > key || (k2 == key && i2 < idx)) { key = k2; idx = i2; }
    }
    // idx is wave-uniform; fetch the UNBIASED score of the winner
    const float cand = (idx < 64) ? s0 : s1;
    const float sw = __shfl(cand, idx & 63);
    ss = fmaf(sw, sw, ss);
    if (lane == r) { myv = sw; myi = idx; }
    if (lane == (idx & 63)) { if (idx < 64) b0 = -INFINITY; else b1 = -INFINITY; }
  }

  const float inv = 1.f / sqrtf(ss);
  if (lane < 8) {
    outW[(size_t)token * 8 + lane] = myv * inv;
    outI[(size_t)token * 8 + lane] = (float)myi;
  }
}

extern "C" void kernel_launch(void* const* d_in, const int* in_sizes, int n_in,
                              void* d_out, int out_size, void* d_ws, size_t ws_size,
                              hipStream_t stream) {
  const float* x    = (const float*)d_in[0];
  const float* w    = (const float*)d_in[1];
  const float* bias = (const float*)d_in[2];
  float* out = (float*)d_out;

  const int N = in_sizes[0] / DMODEL;  // 16384 tokens
  float* part = (float*)d_ws;

  // pick the largest split-K the workspace can hold
  int KS = 4;
  const size_t perK = (size_t)N * NE * sizeof(float);  // 8.4 MB
  if (ws_size < 4 * perK) KS = 2;
  if (ws_size < 2 * perK) KS = 1;

  logits_partial<<<dim3(N / MT, KS), 256, 0, stream>>>(x, w, part, DMODEL / KS, N);
  router_topk<<<(N + 3) / 4, 256, 0, stream>>>(part, bias, out, out + (size_t)N * 8, KS, N);
}

// Round 2
// 284.877 us; speedup vs baseline: 1.0087x; 1.0087x over previous
//
#include <hip/hip_runtime.h>
#include <hip/hip_bf16.h>
#include <math.h>

// MoE Router V2: x(16384,2048) fp32, W(128,2048) fp32, bias(128) fp32
// out = [weights(16384,8) fp32 | indices(16384,8) as fp32]
//
// Kernel A: fp32 logits GEMM with split-K, partials in d_ws.
//   R2 change: tile 64 tok x 128 exp (was 128x128) -> grid 1024 blocks
//   = 4 blocks/CU = 4 waves/SIMD (was 2) to hide LDS latency/barriers.
//   Per-thread 8x4 accumulators.
// Kernel B: combine partials + softmax + stable top-8 + L2 normalize.

#define MT   64    // tokens per tile
#define NE   128   // experts (fixed)
#define DC   32    // d-chunk staged in LDS
#define XPAD 68    // x tile padded row (16B-aligned reads, 4-way write conflict max)
#define WPAD 132   // w tile padded row
#define DMODEL 2048

__global__ __launch_bounds__(256, 4) void logits_partial(
    const float* __restrict__ x, const float* __restrict__ w,
    float* __restrict__ part, int dPerSplit, int N) {
  __shared__ float xs[DC][XPAD];
  __shared__ float wsm[DC][WPAD];
  const int tid = threadIdx.x;
  const int tx = tid & 31;        // expert group 0..31 (4 experts each)
  const int ty = tid >> 5;        // token group 0..7  (8 tokens each)
  const int e0 = tx * 4;
  const int t0 = ty * 8;
  const size_t tokBase = (size_t)blockIdx.x * MT;
  const int d0 = blockIdx.y * dPerSplit;

  float acc[8][4];
#pragma unroll
  for (int i = 0; i < 8; ++i)
#pragma unroll
    for (int j = 0; j < 4; ++j) acc[i][j] = 0.f;

  const int rs = tid >> 3;        // 0..31
  const int cc = tid & 7;         // float4 column (d = 4*cc)

  for (int dc = 0; dc < dPerSplit; dc += DC) {
    __syncthreads();
    // stage x[64 tok][32 d] transposed into LDS [d][tok]
#pragma unroll
    for (int j = 0; j < 2; ++j) {
      const int r = rs + j * 32;
      const float4 xv = *(const float4*)(x + (tokBase + r) * DMODEL + d0 + dc + cc * 4);
      const int dd = cc * 4;
      xs[dd + 0][r] = xv.x; xs[dd + 1][r] = xv.y;
      xs[dd + 2][r] = xv.z; xs[dd + 3][r] = xv.w;
    }
    // stage w[128 exp][32 d] transposed into LDS [d][exp]
#pragma unroll
    for (int j = 0; j < 4; ++j) {
      const int r = rs + j * 32;
      const float4 wv = *(const float4*)(w + (size_t)r * DMODEL + d0 + dc + cc * 4);
      const int dd = cc * 4;
      wsm[dd + 0][r] = wv.x; wsm[dd + 1][r] = wv.y;
      wsm[dd + 2][r] = wv.z; wsm[dd + 3][r] = wv.w;
    }
    __syncthreads();
#pragma unroll 8
    for (int d = 0; d < DC; ++d) {
      const float4 xa = *(const float4*)&xs[d][t0];
      const float4 xb = *(const float4*)&xs[d][t0 + 4];
      const float4 wa = *(const float4*)&wsm[d][e0];
      const float xr[8] = {xa.x, xa.y, xa.z, xa.w, xb.x, xb.y, xb.z, xb.w};
      const float wr[4] = {wa.x, wa.y, wa.z, wa.w};
#pragma unroll
      for (int i = 0; i < 8; ++i)
#pragma unroll
        for (int jj = 0; jj < 4; ++jj)
          acc[i][jj] = fmaf(xr[i], wr[jj], acc[i][jj]);
    }
  }

  const size_t pBase = ((size_t)blockIdx.y * N + tokBase + t0) * NE + e0;
#pragma unroll
  for (int i = 0; i < 8; ++i) {
    float4 v = make_float4(acc[i][0], acc[i][1], acc[i][2], acc[i][3]);
    *(float4*)(part + pBase + (size_t)i * NE) = v;
  }
}

// One wave (64 lanes) per token; lane owns experts {lane, lane+64}.
__global__ __launch_bounds__(256) void router_topk(
    const float* __restrict__ part, const float* __restrict__ bias,
    float* __restrict__ outW, float* __restrict__ outI, int KS, int N) {
  const int wave = threadIdx.x >> 6;
  const int lane = threadIdx.x & 63;
  const int token = blockIdx.x * 4 + wave;
  if (token >= N) return;

  // deterministic combine of split-K partials (fixed order k=0..KS-1)
  float l0 = 0.f, l1 = 0.f;
  for (int k = 0; k < KS; ++k) {
    const float* p = part + ((size_t)k * N + token) * NE;
    l0 += p[lane];
    l1 += p[lane + 64];
  }

  // softmax over 128 experts
  float m = fmaxf(l0, l1);
#pragma unroll
  for (int off = 1; off < 64; off <<= 1) m = fmaxf(m, __shfl_xor(m, off));
  const float ev0 = __expf(l0 - m);
  const float ev1 = __expf(l1 - m);
  float zs = ev0 + ev1;
#pragma unroll
  for (int off = 1; off < 64; off <<= 1) zs += __shfl_xor(zs, off);
  const float s0 = ev0 / zs;
  const float s1 = ev1 / zs;

  // bias-adjusted selection keys (bias affects selection only)
  float b0 = s0 + bias[lane];
  float b1 = s1 + bias[lane + 64];

  float myv = 0.f;
  int myi = 0;
  float ss = 0.f;
#pragma unroll
  for (int r = 0; r < 8; ++r) {
    // lane-local best (tie -> smaller index; lane < lane+64 so >=)
    float key; int idx;
    if (b0 >= b1) { key = b0; idx = lane; }
    else          { key = b1; idx = lane + 64; }
    // wave argmax, stable (tie -> smaller index), matches lax.top_k
#pragma unroll
    for (int off = 1; off < 64; off <<= 1) {
      const float k2 = __shfl_xor(key, off);
      const int   i2 = __shfl_xor(idx, off);
      if (k2 > key || (k2 == key && i2 < idx)) { key = k2; idx = i2; }
    }
    // idx is wave-uniform; fetch the UNBIASED score of the winner
    const float cand = (idx < 64) ? s0 : s1;
    const float sw = __shfl(cand, idx & 63);
    ss = fmaf(sw, sw, ss);
    if (lane == r) { myv = sw; myi = idx; }
    if (lane == (idx & 63)) { if (idx < 64) b0 = -INFINITY; else b1 = -INFINITY; }
  }

  const float inv = 1.f / sqrtf(ss);
  if (lane < 8) {
    outW[(size_t)token * 8 + lane] = myv * inv;
    outI[(size_t)token * 8 + lane] = (float)myi;
  }
}

extern "C" void kernel_launch(void* const* d_in, const int* in_sizes, int n_in,
                              void* d_out, int out_size, void* d_ws, size_t ws_size,
                              hipStream_t stream) {
  const float* x    = (const float*)d_in[0];
  const float* w    = (const float*)d_in[1];
  const float* bias = (const float*)d_in[2];
  float* out = (float*)d_out;

  const int N = in_sizes[0] / DMODEL;  // 16384 tokens
  float* part = (float*)d_ws;

  // pick the largest split-K the workspace can hold
  int KS = 4;
  const size_t perK = (size_t)N * NE * sizeof(float);  // 8.4 MB
  if (ws_size < 4 * perK) KS = 2;
  if (ws_size < 2 * perK) KS = 1;

  logits_partial<<<dim3(N / MT, KS), 256, 0, stream>>>(x, w, part, DMODEL / KS, N);
  router_topk<<<(N + 3) / 4, 256, 0, stream>>>(part, bias, out, out + (size_t)N * 8, KS, N);
}

// Round 3
// 224.250 us; speedup vs baseline: 1.2814x; 1.2704x over previous
//
#include <hip/hip_runtime.h>
#include <hip/hip_bf16.h>
#include <math.h>

// MoE Router V2: x(16384,2048) fp32, W(128,2048) fp32, bias(128) fp32
// out = [weights(16384,8) fp32 | indices(16384,8) as fp32]
//
// R3: logits GEMM via split-bf16 MFMA (Ozaki-style 3-plane truncation,
//     6 cross-product MFMAs = fp32-accurate). 128x128 tile, KS=4 split-K.
//     Truncation split is EXACT (x = x1+x2+x3 + r, |r|<2^-23|x|); dropped
//     cross terms ~2^-24 rel -> logit err ~2e-7 << fp32 chain err.
// Kernel B: combine partials + softmax + stable top-8 + L2 normalize.

#define NE     128
#define TOKT   128   // tokens per tile
#define KC     32    // k per chunk (one 16x16x32 MFMA step)
#define KS     4     // split-K
#define DMODEL 2048
#define DSLICE (DMODEL / KS)  // 512

typedef __attribute__((ext_vector_type(8))) short short8;
typedef __attribute__((ext_vector_type(4))) float f32x4;

union S8 { short s[8]; short8 v; };

// split one fp32 into 3 truncated bf16 planes (exact residuals)
__device__ __forceinline__ void split3(float f, S8& hi, S8& mi, S8& lo, int j) {
  const unsigned u0 = __float_as_uint(f);
  const float hif = __uint_as_float(u0 & 0xFFFF0000u);
  const float r1 = f - hif;                      // exact
  const unsigned u1 = __float_as_uint(r1);
  const float mif = __uint_as_float(u1 & 0xFFFF0000u);
  const float r2 = r1 - mif;                     // exact
  hi.s[j] = (short)(u0 >> 16);
  mi.s[j] = (short)(u1 >> 16);
  lo.s[j] = (short)(__float_as_uint(r2) >> 16);
}

__global__ __launch_bounds__(256) void logits_mfma(
    const float* __restrict__ x, const float* __restrict__ w,
    float* __restrict__ part, int N) {
  // 3 bf16 planes per operand, [plane][row][k]: row stride 32 bf16 = 64 B,
  // frag reads cover a contiguous 1 KiB per wave -> conflict-free b128.
  __shared__ short xs[3][TOKT][KC];
  __shared__ short wsm[3][NE][KC];

  const int tid  = threadIdx.x;
  const int wave = tid >> 6;
  const int lane = tid & 63;
  const int wm = wave >> 1;        // wave-grid 2x2: m half
  const int wn = wave & 1;         // n half
  const int quad = lane >> 4;
  const int l16  = lane & 15;
  const size_t tokBase = (size_t)blockIdx.x * TOKT;
  const int d0 = blockIdx.y * DSLICE;

  // staging assignment: 2 threads per row, 16 consecutive k each
  const int r = tid >> 1;          // row 0..127 (token row and expert row)
  const int h = tid & 1;           // k half (0 or 16)

  f32x4 acc[4][4];
#pragma unroll
  for (int i = 0; i < 4; ++i)
#pragma unroll
    for (int j = 0; j < 4; ++j) acc[i][j] = (f32x4)(0.f);

  for (int kc = 0; kc < DSLICE; kc += KC) {
    __syncthreads();
    // ---- stage x and w: fp32 -> 3 bf16 planes, two 8-k runs per thread ----
    {
      const float* gx = x + (tokBase + r) * DMODEL + d0 + kc + h * 16;
      const float* gw = w + (size_t)r * DMODEL + d0 + kc + h * 16;
#pragma unroll
      for (int run = 0; run < 2; ++run) {
        const float4 a0 = *(const float4*)(gx + run * 8);
        const float4 a1 = *(const float4*)(gx + run * 8 + 4);
        S8 hi, mi, lo;
        split3(a0.x, hi, mi, lo, 0); split3(a0.y, hi, mi, lo, 1);
        split3(a0.z, hi, mi, lo, 2); split3(a0.w, hi, mi, lo, 3);
        split3(a1.x, hi, mi, lo, 4); split3(a1.y, hi, mi, lo, 5);
        split3(a1.z, hi, mi, lo, 6); split3(a1.w, hi, mi, lo, 7);
        const int kk = h * 16 + run * 8;
        *(short8*)&xs[0][r][kk] = hi.v;
        *(short8*)&xs[1][r][kk] = mi.v;
        *(short8*)&xs[2][r][kk] = lo.v;
        const float4 b0 = *(const float4*)(gw + run * 8);
        const float4 b1 = *(const float4*)(gw + run * 8 + 4);
        split3(b0.x, hi, mi, lo, 0); split3(b0.y, hi, mi, lo, 1);
        split3(b0.z, hi, mi, lo, 2); split3(b0.w, hi, mi, lo, 3);
        split3(b1.x, hi, mi, lo, 4); split3(b1.y, hi, mi, lo, 5);
        split3(b1.z, hi, mi, lo, 6); split3(b1.w, hi, mi, lo, 7);
        *(short8*)&wsm[0][r][kk] = hi.v;
        *(short8*)&wsm[1][r][kk] = mi.v;
        *(short8*)&wsm[2][r][kk] = lo.v;
      }
    }
    __syncthreads();

    // ---- fragments + 6-plane MFMAs ----
    short8 af[4][3];
#pragma unroll
    for (int mt = 0; mt < 4; ++mt)
#pragma unroll
      for (int p = 0; p < 3; ++p)
        af[mt][p] = *(const short8*)&xs[p][wm * 64 + mt * 16 + l16][quad * 8];

#pragma unroll
    for (int nt = 0; nt < 4; ++nt) {
      short8 bf[3];
#pragma unroll
      for (int p = 0; p < 3; ++p)
        bf[p] = *(const short8*)&wsm[p][wn * 64 + nt * 16 + l16][quad * 8];
#pragma unroll
      for (int mt = 0; mt < 4; ++mt) {
        f32x4 c = acc[mt][nt];
        c = __builtin_amdgcn_mfma_f32_16x16x32_bf16(af[mt][0], bf[0], c, 0, 0, 0); // x1w1
        c = __builtin_amdgcn_mfma_f32_16x16x32_bf16(af[mt][0], bf[1], c, 0, 0, 0); // x1w2
        c = __builtin_amdgcn_mfma_f32_16x16x32_bf16(af[mt][1], bf[0], c, 0, 0, 0); // x2w1
        c = __builtin_amdgcn_mfma_f32_16x16x32_bf16(af[mt][0], bf[2], c, 0, 0, 0); // x1w3
        c = __builtin_amdgcn_mfma_f32_16x16x32_bf16(af[mt][2], bf[0], c, 0, 0, 0); // x3w1
        c = __builtin_amdgcn_mfma_f32_16x16x32_bf16(af[mt][1], bf[1], c, 0, 0, 0); // x2w2
        acc[mt][nt] = c;
      }
    }
  }

  // ---- epilogue: partials[kb][tok][exp]; C/D: col=lane&15, row=quad*4+reg ----
#pragma unroll
  for (int mt = 0; mt < 4; ++mt)
#pragma unroll
    for (int nt = 0; nt < 4; ++nt) {
      const int ex = wn * 64 + nt * 16 + l16;
#pragma unroll
      for (int reg = 0; reg < 4; ++reg) {
        const size_t tok = tokBase + wm * 64 + mt * 16 + quad * 4 + reg;
        part[((size_t)blockIdx.y * N + tok) * NE + ex] = acc[mt][nt][reg];
      }
    }
}

// One wave (64 lanes) per token; lane owns experts {lane, lane+64}.
__global__ __launch_bounds__(256) void router_topk(
    const float* __restrict__ part, const float* __restrict__ bias,
    float* __restrict__ outW, float* __restrict__ outI, int ks, int N) {
  const int wave = threadIdx.x >> 6;
  const int lane = threadIdx.x & 63;
  const int token = blockIdx.x * 4 + wave;
  if (token >= N) return;

  float l0 = 0.f, l1 = 0.f;
  for (int k = 0; k < ks; ++k) {
    const float* p = part + ((size_t)k * N + token) * NE;
    l0 += p[lane];
    l1 += p[lane + 64];
  }

  float m = fmaxf(l0, l1);
#pragma unroll
  for (int off = 1; off < 64; off <<= 1) m = fmaxf(m, __shfl_xor(m, off));
  const float ev0 = __expf(l0 - m);
  const float ev1 = __expf(l1 - m);
  float zs = ev0 + ev1;
#pragma unroll
  for (int off = 1; off < 64; off <<= 1) zs += __shfl_xor(zs, off);
  const float s0 = ev0 / zs;
  const float s1 = ev1 / zs;

  float b0 = s0 + bias[lane];
  float b1 = s1 + bias[lane + 64];

  float myv = 0.f;
  int myi = 0;
  float ss = 0.f;
#pragma unroll
  for (int rnd = 0; rnd < 8; ++rnd) {
    float key; int idx;
    if (b0 >= b1) { key = b0; idx = lane; }
    else          { key = b1; idx = lane + 64; }
#pragma unroll
    for (int off = 1; off < 64; off <<= 1) {
      const float k2 = __shfl_xor(key, off);
      const int   i2 = __shfl_xor(idx, off);
      if (k2 > key || (k2 == key && i2 < idx)) { key = k2; idx = i2; }
    }
    const float cand = (idx < 64) ? s0 : s1;
    const float sw = __shfl(cand, idx & 63);
    ss = fmaf(sw, sw, ss);
    if (lane == rnd) { myv = sw; myi = idx; }
    if (lane == (idx & 63)) { if (idx < 64) b0 = -INFINITY; else b1 = -INFINITY; }
  }

  const float inv = 1.f / sqrtf(ss);
  if (lane < 8) {
    outW[(size_t)token * 8 + lane] = myv * inv;
    outI[(size_t)token * 8 + lane] = (float)myi;
  }
}

extern "C" void kernel_launch(void* const* d_in, const int* in_sizes, int n_in,
                              void* d_out, int out_size, void* d_ws, size_t ws_size,
                              hipStream_t stream) {
  const float* x    = (const float*)d_in[0];
  const float* w    = (const float*)d_in[1];
  const float* bias = (const float*)d_in[2];
  float* out = (float*)d_out;

  const int N = in_sizes[0] / DMODEL;  // 16384 tokens
  float* part = (float*)d_ws;          // KS * N * 128 * 4 B = 33.5 MB

  logits_mfma<<<dim3(N / TOKT, KS), 256, 0, stream>>>(x, w, part, N);
  router_topk<<<(N + 3) / 4, 256, 0, stream>>>(part, bias, out, out + (size_t)N * 8, KS, N);
}